// Round 12
// baseline (127.386 us; speedup 1.0000x reference)
//
#include <hip/hip_runtime.h>

// Pink-noise 6-pole IIR — warmup-tile parallel, all-register, ONE barrier.
//
// Decomposition (proven r5-r11): slowest pole 0.99886 -> A^8192 = 8.7e-5, so
// each block computes one 8192-sample output tile from zero state preceded by
// an 8192-sample warmup. Truncation error ~1e-4 (passes since r5); tile 0 of
// each channel is EXACT. XCD-swizzled block ids (r11-proven: FETCH halved —
// tile t's data re-read as tile t+1's warmup is an L2 hit).
//
// Round-11 lesson: reusing one register set for warmup-then-tile serializes
// TWO HBM round trips per block (load-wait -> scan -> load-wait -> scan);
// hbm 1.7 TB/s, dur 58.8 µs. Fix: issue ALL 8 float4 loads up-front into
// SEPARATE registers (y* warmup, x* tile) — one round trip; the warmup scan
// waits vmcnt(4), the tile scan vmcnt(0) (compiler's counted waits).
// This needs the 128-reg bin: __launch_bounds__(512,2) (r4-proven no-spill;
// occupancy model r4/r5/r8/r9: wave slots quantize at VGPR 64/128/256).
// Fold constants (pmL/Mwv) are computed AFTER the barrier where data regs
// are dead, keeping the scan-phase live set ~110 < 128.
// Spill tripwire: WRITE_SIZE >> 66 MB next round => live set overflowed.

constexpr int kL = 65536;               // samples per channel
constexpr int kThr = 512;               // threads per block = 8 waves
constexpr int kWaves = kThr / 64;       // 8
constexpr int kPT = 16;                 // contiguous samples per thread/region
constexpr int kT = kThr * kPT;          // 8192 output tile per block
constexpr int kW = 8192;                // warmup samples
constexpr int kTilesPerCh = kL / kT;    // 8

__global__ __launch_bounds__(kThr, 2) void pink_tile(
    const float* __restrict__ white, float* __restrict__ pink, int nBlk)
{
    constexpr float A[6] = {0.99886f, 0.99332f, 0.969f, 0.8665f, 0.55f, -0.7616f};
    constexpr float C[6] = {0.0555179f, 0.0750759f, 0.153852f, 0.3104856f, 0.5329522f, -0.016898f};
    constexpr float B6G = 0.115926f, DIRECT = 0.5362f, OUTG = 0.11f;

    __shared__ float swvA[6][kWaves];    // warmup wave totals (u-space)
    __shared__ float swvB[6][kWaves];    // tile wave totals (u-space)
    __shared__ float lastwB[kWaves];     // last tile sample per wave
    __shared__ float sLastWarm;          // last warmup sample of the block

    const int tid = threadIdx.x, lane = tid & 63, wave = tid >> 6;

    // XCD-aware swizzle (bijective: nBlk % 8 == 0): a channel's 8 tiles stay
    // on one XCD so warmup re-reads hit that XCD's L2.
    const int cpx = nBlk >> 3;
    const int vb = (blockIdx.x & 7) * cpx + (blockIdx.x >> 3);
    const int ch = vb / kTilesPerCh;
    const int tI = vb % kTilesPerCh;
    const size_t outBase = (size_t)ch * kL + (size_t)tI * kT;

    // ---- Issue ALL loads up-front: one HBM round trip per block ----
    const float* gB = white + outBase + (size_t)kPT * tid;
    float4 y0, y1, y2, y3;               // warmup samples
    if (tI != 0) {
        const float* gA = gB - kW;
        y0 = *(const float4*)(gA);
        y1 = *(const float4*)(gA + 4);
        y2 = *(const float4*)(gA + 8);
        y3 = *(const float4*)(gA + 12);
    } else {
        y0 = y1 = y2 = y3 = make_float4(0.f, 0.f, 0.f, 0.f);
    }
    float4 x0 = *(const float4*)(gB);    // tile samples
    float4 x1 = *(const float4*)(gB + 4);
    float4 x2 = *(const float4*)(gB + 8);
    float4 x3 = *(const float4*)(gB + 12);

    #define SCAN4(V, E) { \
        const float* _p = &(V).x; \
        _Pragma("unroll") \
        for (int j = 0; j < 4; ++j) { \
            const float ww = _p[j]; \
            _Pragma("unroll") \
            for (int p = 0; p < 6; ++p) (E)[p] = fmaf(A[p], (E)[p], ww); \
        } }

    // ---- Warmup scan (u-space: u = A*u + w); waits only on the y loads ----
    float eA[6] = {0.f, 0.f, 0.f, 0.f, 0.f, 0.f};
    if (tI != 0) { SCAN4(y0, eA) SCAN4(y1, eA) SCAN4(y2, eA) SCAN4(y3, eA) }
    if (tid == kThr - 1) sLastWarm = y3.w;   // 0 when tI==0; barrier covers

    // ---- Tile scan ----
    float eB[6] = {0.f, 0.f, 0.f, 0.f, 0.f, 0.f};
    SCAN4(x0, eB) SCAN4(x1, eB) SCAN4(x2, eB) SCAN4(x3, eB)
    #undef SCAN4

    // ---- Shared wave affine scan (A and B interleaved, shared mk) ----
    float mk[6];
    #pragma unroll
    for (int p = 0; p < 6; ++p) {
        float q = A[p];
        #pragma unroll
        for (int i = 0; i < 4; ++i) q *= q;      // A^16
        mk[p] = q;
    }
    #pragma unroll
    for (int r = 0; r < 6; ++r) {
        const int off = 1 << r;
        float fA[6], fB[6];
        #pragma unroll
        for (int p = 0; p < 6; ++p) { fA[p] = __shfl_up(eA[p], off);
                                      fB[p] = __shfl_up(eB[p], off); }
        if (lane >= off) {
            #pragma unroll
            for (int p = 0; p < 6; ++p) { eA[p] = fmaf(mk[p], fA[p], eA[p]);
                                          eB[p] = fmaf(mk[p], fB[p], eB[p]); }
        }
        #pragma unroll
        for (int p = 0; p < 6; ++p) mk[p] *= mk[p];
    }
    float ex[6];
    #pragma unroll
    for (int p = 0; p < 6; ++p) {
        ex[p] = __shfl_up(eB[p], 1);
        if (lane == 0) ex[p] = 0.f;
    }
    if (lane == 63) {
        #pragma unroll
        for (int p = 0; p < 6; ++p) { swvA[p][wave] = eA[p];
                                      swvB[p][wave] = eB[p]; }
        lastwB[wave] = x3.w;
    }
    __syncthreads();                 // the ONLY barrier

    // ---- Fold constants (computed here: scan-phase registers are dead) ----
    // pmL = (A^16)^lane, Mwv = (A^16)^64 = A^1024. Underflow-to-0 for fast
    // poles is numerically correct.
    float pmL[6], Mwv[6];
    #pragma unroll
    for (int p = 0; p < 6; ++p) {
        float q = A[p];
        #pragma unroll
        for (int i = 0; i < 4; ++i) q *= q;      // A^16
        float pm = 1.f;
        #pragma unroll
        for (int b = 0; b < 6; ++b) { if ((lane >> b) & 1) pm *= q; q *= q; }
        pmL[p] = pm;
        Mwv[p] = q;                               // A^1024
    }

    // ---- Fold: warmup end state R -> prior tile waves -> lane span ----
    float ub[6];
    #pragma unroll
    for (int p = 0; p < 6; ++p) {
        float R = 0.f;
        #pragma unroll
        for (int w2 = 0; w2 < kWaves; ++w2) R = fmaf(Mwv[p], R, swvA[p][w2]);
        float X = R;
        #pragma unroll
        for (int w2 = 0; w2 < kWaves; ++w2)
            if (w2 < wave) X = fmaf(Mwv[p], X, swvB[p][w2]);
        ub[p] = fmaf(pmL[p], X, ex[p]);
    }

    // Previous white sample for the b6 delay line.
    float pwl = __shfl_up(x3.w, 1);
    if (lane == 0) pwl = (wave == 0) ? sLastWarm : lastwB[wave - 1];
    float b6 = B6G * pwl;

    // ---- Recompute + store directly from registers ----
    float* dstF = pink + outBase + (size_t)kPT * tid;
    #define EMIT4(V, OFS) { \
        const float* _p = &(V).x; \
        float4 o; float* _o = &o.x; \
        _Pragma("unroll") \
        for (int j = 0; j < 4; ++j) { \
            const float ww = _p[j]; \
            _Pragma("unroll") \
            for (int p = 0; p < 6; ++p) ub[p] = fmaf(A[p], ub[p], ww); \
            float t0 = C[0] * ub[0];  t0 = fmaf(C[1], ub[1], t0); \
            float t1 = C[2] * ub[2];  t1 = fmaf(C[3], ub[3], t1); \
            float t2 = C[4] * ub[4];  t2 = fmaf(C[5], ub[5], t2); \
            const float sum = (t0 + t1) + (t2 + b6); \
            _o[j] = fmaf(DIRECT, ww, sum) * OUTG; \
            b6 = B6G * ww; \
        } \
        *(float4*)(dstF + (OFS)) = o; }
    EMIT4(x0, 0) EMIT4(x1, 4) EMIT4(x2, 8) EMIT4(x3, 12)
    #undef EMIT4
}

extern "C" void kernel_launch(void* const* d_in, const int* in_sizes, int n_in,
                              void* d_out, int out_size, void* d_ws, size_t ws_size,
                              hipStream_t stream) {
    const float* white = (const float*)d_in[0];
    float* pink = (float*)d_out;
    const int nCh = in_sizes[0] / kL;                 // 256 channels
    const int nBlk = nCh * kTilesPerCh;               // 2048 blocks (8|2048)

    hipLaunchKernelGGL(pink_tile, dim3(nBlk), dim3(kThr), 0, stream,
                       white, pink, nBlk);
}